// Round 8
// baseline (192.630 us; speedup 1.0000x reference)
//
#include <hip/hip_runtime.h>

// Problem constants (fixed by the reference)
#define N_NODES 20000
#define N_EDGES 320000
#define ETOT    (N_EDGES + N_NODES)   // edges + self-loops = 340000
#define HEADS   10
#define F_IN    32
#define C1      (HEADS * F_IN)        // 320
#define C2      128
#define NB      100
#define PER     200
#define CAP     96                    // CSR bucket capacity (max in-degree << 96)
#define SSTRIDE 12                    // padded score row stride (floats, 48B = 16B-aligned)
#define HSTRIDE 328                   // padded tile row stride (ushort); 328*2=656 is 16B-aligned
#define X2STRIDE 136                  // padded x2-tile row stride (f16); 136*2=272 is 16B-aligned
#define NZCNT   (N_NODES + NB * C2 + NB)   // cursor + pooledi + done (ints)

typedef __attribute__((ext_vector_type(8))) short bf16x8;   // MFMA A/B frag (4 VGPRs)
typedef __attribute__((ext_vector_type(4))) float floatx4;  // MFMA C/D frag
typedef _Float16 f16;
typedef _Float16 f16x2 __attribute__((ext_vector_type(2)));
typedef _Float16 f16x4 __attribute__((ext_vector_type(4)));
typedef _Float16 f16x8 __attribute__((ext_vector_type(8)));

static __device__ __forceinline__ unsigned short f2bf(float f) {
    unsigned int u = __float_as_uint(f);
    unsigned int r = (u + 0x7fffu + ((u >> 16) & 1u)) >> 16;   // RNE
    return (unsigned short)r;
}

// ---------------------------------------------------------------------------
// Fold + zero kernel (round 8): block 0 computes the W1-fold ONCE (was
// redundantly recomputed by all 313 SCORE blocks = 128MB of L2 reads);
// blocks 1..33 zero cursor/pooledi/done (replaces the hipMemsetAsync
// dispatch).  34 blocks x 256.
// ---------------------------------------------------------------------------
__global__ __launch_bounds__(256) void fold_zero_kernel(
        const float* __restrict__ W1, const float* __restrict__ a1s,
        const float* __restrict__ a1d, float* __restrict__ wsF,
        float* __restrict__ wdF, int* __restrict__ zeros) {
    unsigned int b = blockIdx.x;
    int t = threadIdx.x;
    if (b == 0) {
        for (int o = t; o < C1; o += 256) {
            int k = o & 31, h = o >> 5;
            float ss = 0.f, dd = 0.f;
#pragma unroll
            for (int f = 0; f < F_IN; f++) {
                float wv = W1[k * C1 + h * 32 + f];
                ss += wv * a1s[h * 32 + f];
                dd += wv * a1d[h * 32 + f];
            }
            wsF[k * HEADS + h] = ss;
            wdF[k * HEADS + h] = dd;
        }
        return;
    }
    // zero region, int4 stores (region is 256B-aligned)
    int i = (b - 1) * 256 + t;                 // int4 index
    const int n4 = (NZCNT + 3) / 4;            // 8225
    if (i < n4) {
        int4 z = {0, 0, 0, 0};
        ((int4*)zeros)[i] = z;                 // NZCNT rounded up: alloc padded to 256B
    }
}

// ---------------------------------------------------------------------------
// Mega prep: CSR scatter + layer-1 scores (folded WA from fold_zero_kernel)
// + W2/W1/FC B-frag prep + feats->f16.
// ---------------------------------------------------------------------------
#define SCAT_BLOCKS  ((ETOT + 255) / 256)               // 1329
#define SCORE_BLOCKS ((N_NODES + 63) / 64)              // 313
#define W2P_BLOCKS   ((C1 * C2 + 255) / 256)            // 160
#define W1P_BLOCKS   ((HEADS * F_IN * F_IN + 255) / 256)// 40
#define FCP_BLOCKS   ((C2 * C2 + 255) / 256)            // 64
#define F16_BLOCKS   ((N_NODES * F_IN / 4 + 255) / 256) // 625
__global__ __launch_bounds__(256) void mega_prep_kernel(
        const int* __restrict__ ei, int* __restrict__ cursor, int* __restrict__ csr_src,
        const float* __restrict__ feats, f16* __restrict__ feats16,
        const float* __restrict__ W1, unsigned short* __restrict__ W1p,
        const float* __restrict__ W2, unsigned short* __restrict__ W2p,
        const float* __restrict__ fcw, f16* __restrict__ FCp,
        const float* __restrict__ wsF, const float* __restrict__ wdF,
        float* __restrict__ s_src, float* __restrict__ s_dst) {
    unsigned int b = blockIdx.x;
    if (b < SCAT_BLOCKS) {
        int e = b * 256 + threadIdx.x;
        if (e >= ETOT) return;
        int s, d;
        if (e < N_EDGES) { s = ei[e]; d = ei[N_EDGES + e]; }
        else             { s = e - N_EDGES; d = s; }
        int pos = atomicAdd(&cursor[d], 1);
        csr_src[(size_t)d * CAP + pos] = s;
        return;
    }
    b -= SCAT_BLOCKS;
    if (b < SCORE_BLOCKS) {
        __shared__ __align__(16) float A[64 * F_IN];   // 8 KB
        __shared__ float Ws[C1], Wd[C1];
        int t = threadIdx.x;
        // load the pre-folded attention-through-W1 vectors (2.5 KB total)
        for (int o = t; o < C1; o += 256) {
            Ws[o] = wsF[o];
            Wd[o] = wdF[o];
        }
        int n0 = b * 64;
        int nrows = min(64, N_NODES - n0);
        const float4* fs = (const float4*)(feats + (size_t)n0 * F_IN);
        float4* Af = (float4*)A;
        for (int i = t; i < nrows * 8; i += 256) Af[i] = fs[i];
        __syncthreads();
        for (int o = t; o < nrows * HEADS; o += 256) {
            int nl = o / HEADS, h = o - nl * HEADS;
            const float* ar = A + nl * F_IN;
            float ss = 0.f, dd = 0.f;
#pragma unroll
            for (int k = 0; k < F_IN; k++) {
                float av = ar[k];
                ss += av * Ws[k * HEADS + h];
                dd += av * Wd[k * HEADS + h];
            }
            s_src[(size_t)(n0 + nl) * SSTRIDE + h] = ss;
            s_dst[(size_t)(n0 + nl) * SSTRIDE + h] = dd;
        }
        return;
    }
    b -= SCORE_BLOCKS;
    if (b < W2P_BLOCKS) {
        int o = b * 256 + threadIdx.x;   // 40960
        if (o >= C1 * C2) return;
        int j    = o & 7;
        int lane = (o >> 3) & 63;
        int ct   = (o >> 9) & 7;
        int kb   = o >> 12;
        int k = kb * 32 + (lane >> 4) * 8 + j;
        int n = ct * 16 + (lane & 15);
        W2p[o] = f2bf(W2[k * C2 + n]);
        return;
    }
    b -= W2P_BLOCKS;
    if (b < W1P_BLOCKS) {
        int o = b * 256 + threadIdx.x;   // 10240
        if (o >= HEADS * F_IN * F_IN) return;
        int j    = o & 7;
        int lane = (o >> 3) & 63;
        int ct   = (o >> 9) & 1;
        int h    = o >> 10;
        int k = (lane >> 4) * 8 + j;
        int f = ct * 16 + (lane & 15);
        W1p[o] = f2bf(W1[k * C1 + h * 32 + f]);
        return;
    }
    b -= W1P_BLOCKS;
    if (b < FCP_BLOCKS) {
        int o = b * 256 + threadIdx.x;   // 16384
        if (o >= C2 * C2) return;
        int j    = o & 7;
        int lane = (o >> 3) & 63;
        int ct   = (o >> 9) & 7;
        int kb   = o >> 12;
        int k = kb * 32 + (lane >> 4) * 8 + j;
        int n = ct * 16 + (lane & 15);
        FCp[o] = (f16)fcw[k * C2 + n];
        return;
    }
    b -= FCP_BLOCKS;
    {
        int o = b * 256 + threadIdx.x;
        if (o < N_NODES * F_IN / 4) {
            float4 v = ((const float4*)feats)[o];
            f16* d = feats16 + 4 * o;
            d[0] = (f16)v.x; d[1] = (f16)v.y; d[2] = (f16)v.z; d[3] = (f16)v.w;
        }
    }
}

// ---------------------------------------------------------------------------
// FUSED layer-1 aggregation + h1 transform + gemm2.  512 threads, one node
// per 32-lane half-wave.  Fixed 8-group gather (R7 structure, unchanged).
// ---------------------------------------------------------------------------
__global__ __launch_bounds__(512) void agg1h1g2_kernel(
        const f16* __restrict__ feats16, const float* __restrict__ s_src,
        const float* __restrict__ s_dst, const int* __restrict__ deg_arr,
        const int* __restrict__ csr_src,
        const unsigned short* __restrict__ W1p, const float* __restrict__ b1,
        const unsigned short* __restrict__ W2p,
        const float* __restrict__ a_src, const float* __restrict__ a_dst,
        f16* __restrict__ xw2h, float* __restrict__ s_src2, float* __restrict__ s_dst2) {
    union Smem {
        struct { f16 P[16][HEADS * 32]; int S[16][32]; } p1;  // 10 KB + 2 KB
        unsigned short H[16 * HSTRIDE];                       // 10.25 KB
    };
    __shared__ __align__(16) Smem u;
    __shared__ __align__(16) unsigned short G[16 * HSTRIDE];  // gn tile, bf16
    __shared__ float redS[8][16], redD[8][16];

    int tid   = threadIdx.x;
    int wslot = tid >> 6;          // 0..7
    int lane  = tid & 63;
    int r     = tid >> 5;          // 0..15: node slot (one per half-wave)
    int l     = tid & 31;          // k-index and edge-slot
    int row0  = blockIdx.x * 16;   // 1250 blocks x 16 nodes
    f16* P = u.p1.P[r];
    int* S = u.p1.S[r];
    const f16x2 ones = {(f16)1.f, (f16)1.f};
    const char* fb = (const char*)feats16 + 2 * l;   // lane's k-column base

    // ---- phase 1: one node per half-wave ----
    {
        int n = row0 + r;
        int beg = n * CAP, deg = deg_arr[n];
        const float* sdp = s_dst + (size_t)n * SSTRIDE;
        float sd[10];
        {
            float4 v0 = *(const float4*)(sdp);
            float4 v1 = *(const float4*)(sdp + 4);
            float2 v2 = *(const float2*)(sdp + 8);
            sd[0]=v0.x; sd[1]=v0.y; sd[2]=v0.z; sd[3]=v0.w;
            sd[4]=v1.x; sd[5]=v1.y; sd[6]=v1.z; sd[7]=v1.w;
            sd[8]=v2.x; sd[9]=v2.y;
        }
        float g[10], la[10];
#pragma unroll
        for (int h = 0; h < 10; h++) { g[h] = 0.f; la[h] = 0.f; }

        for (int c0 = 0; c0 < deg; c0 += 32) {   // lockstep max over wave's 2 halves
            int dc = min(deg - c0, 32);
            bool act = l < dc;
            int s_e = csr_src[beg + c0 + min(l, dc - 1)];
            const float* ssp = s_src + (size_t)s_e * SSTRIDE;
            float ss[10];
            {
                float4 v0 = *(const float4*)(ssp);
                float4 v1 = *(const float4*)(ssp + 4);
                float2 v2 = *(const float2*)(ssp + 8);
                ss[0]=v0.x; ss[1]=v0.y; ss[2]=v0.z; ss[3]=v0.w;
                ss[4]=v1.x; ss[5]=v1.y; ss[6]=v1.z; ss[7]=v1.w;
                ss[8]=v2.x; ss[9]=v2.y;
            }
            float p[10];
#pragma unroll
            for (int h = 0; h < 10; h++) {
                float e0 = ss[h] + sd[h];
                e0 = (e0 >= 0.f) ? e0 : 0.2f * e0;   // leaky_relu(0.2)
                p[h] = act ? __expf(e0) : 0.f;       // pad lanes: exact 0
            }
            S[l] = s_e << 6;   // BYTE offset: row = 32 f16 = 64 B
#pragma unroll
            for (int h = 0; h < 10; h++) P[h * 32 + l] = (f16)p[h];
            asm volatile("s_waitcnt lgkmcnt(0)" ::: "memory");   // staging visible

            // FIXED 8 groups: compile-time trip -> full unroll, loads hoisted
#pragma unroll
            for (int i = 0; i < 32; i += 4) {
                int4 ss4 = *(const int4*)&S[i];
                f16x2 v01, v23;
                v01.x = *(const f16*)(fb + ss4.x);
                v01.y = *(const f16*)(fb + ss4.y);
                v23.x = *(const f16*)(fb + ss4.z);
                v23.y = *(const f16*)(fb + ss4.w);
#pragma unroll
                for (int h = 0; h < 10; h++) {
                    f16x4 pp = *(const f16x4*)&P[h * 32 + i];
                    f16x2 p01 = {pp[0], pp[1]};
                    f16x2 p23 = {pp[2], pp[3]};
                    g[h]  = __builtin_amdgcn_fdot2(p01, v01, g[h], false);
                    g[h]  = __builtin_amdgcn_fdot2(p23, v23, g[h], false);
                    la[h] = __builtin_amdgcn_fdot2(p01, ones, la[h], false);
                    la[h] = __builtin_amdgcn_fdot2(p23, ones, la[h], false);
                }
            }
            asm volatile("s_waitcnt lgkmcnt(0)" ::: "memory");   // P/S reads done before rewrite
        }
        unsigned short* gr = &G[r * HSTRIDE + l];
#pragma unroll
        for (int h = 0; h < 10; h++)
            gr[h * 32] = f2bf(g[h] / fmaxf(la[h], 1e-16f));
    }
    __syncthreads();   // G complete; P/S dead -> union region becomes H

    // ---- phase 2a: h1 = elu(G @ W1 + b1), heads strided over 8 waves ----
    int quad = lane >> 4, col = lane & 15;
    for (int h = wslot; h < 10; h += 8) {
        bf16x8 a = *(const bf16x8*)&G[col * HSTRIDE + h * 32 + quad * 8];
        bf16x8 bA = ((const bf16x8*)W1p)[(h * 2 + 0) * 64 + lane];
        bf16x8 bB = ((const bf16x8*)W1p)[(h * 2 + 1) * 64 + lane];
        floatx4 z = {0.f, 0.f, 0.f, 0.f};
        floatx4 c0 = __builtin_amdgcn_mfma_f32_16x16x32_bf16(a, bA, z, 0, 0, 0);
        floatx4 c1 = __builtin_amdgcn_mfma_f32_16x16x32_bf16(a, bB, z, 0, 0, 0);
        float bias0 = b1[h * 32 + col];
        float bias1 = b1[h * 32 + 16 + col];
#pragma unroll
        for (int reg = 0; reg < 4; reg++) {
            int rr = quad * 4 + reg;
            float o0 = c0[reg] + bias0;
            float o1 = c1[reg] + bias1;
            o0 = (o0 > 0.f) ? o0 : (__expf(o0) - 1.f);
            o1 = (o1 > 0.f) ? o1 : (__expf(o1) - 1.f);
            u.H[rr * HSTRIDE + h * 32 + col]      = f2bf(o0);
            u.H[rr * HSTRIDE + h * 32 + 16 + col] = f2bf(o1);
        }
    }
    __syncthreads();

    // ---- phase 2b: gemm2 — wave w covers col-tile w ----
    floatx4 acc = {0.f, 0.f, 0.f, 0.f};
    const bf16x8* pb = (const bf16x8*)W2p;
#pragma unroll
    for (int kb = 0; kb < 10; kb++) {
        bf16x8 a = *(const bf16x8*)&u.H[col * HSTRIDE + kb * 32 + quad * 8];
        bf16x8 b = pb[(kb * 8 + wslot) * 64 + lane];
        acc = __builtin_amdgcn_mfma_f32_16x16x32_bf16(a, b, acc, 0, 0, 0);
    }
    float asv = a_src[wslot * 16 + col];
    float adv = a_dst[wslot * 16 + col];
#pragma unroll
    for (int reg = 0; reg < 4; reg++) {
        int row = row0 + quad * 4 + reg;
        float v = acc[reg];
        xw2h[(size_t)row * C2 + wslot * 16 + col] = (f16)v;
        float vs = v * asv, vd = v * adv;
#pragma unroll
        for (int off = 8; off >= 1; off >>= 1) {
            vs += __shfl_xor(vs, off);
            vd += __shfl_xor(vd, off);
        }
        if (col == 0) { redS[wslot][quad * 4 + reg] = vs; redD[wslot][quad * 4 + reg] = vd; }
    }
    __syncthreads();
    if (wslot == 0) {
        if (lane < 16) {
            float s = 0.f;
#pragma unroll
            for (int w2 = 0; w2 < 8; w2++) s += redS[w2][lane];
            s_src2[row0 + lane] = s;
        } else if (lane < 32) {
            int r2 = lane - 16;
            float d = 0.f;
#pragma unroll
            for (int w2 = 0; w2 < 8; w2++) d += redD[w2][r2];
            s_dst2[row0 + r2] = d;
        }
    }
}

// ---------------------------------------------------------------------------
// Fused layer-2 aggregation + fc + distributed pooled-fc.  512 threads, one
// node per half-wave, fixed 8-group gather (R7 structure).  Round-8: pooled
// fc fused via per-graph 13-tile completion counter (R5 mechanism, winners
// spread over ~100 distinct blocks; overlaps the kernel tail) — removes the
// separate poolfc dispatch.
// ---------------------------------------------------------------------------
__global__ __launch_bounds__(512) void agg2fc_kernel(
        const f16* __restrict__ xw2h, const float* __restrict__ s_src2,
        const float* __restrict__ s_dst2, const int* __restrict__ deg_arr,
        const int* __restrict__ csr_src, const float* __restrict__ b2,
        const f16* __restrict__ FCp, const float* __restrict__ fcb,
        const float* __restrict__ fcw,
        float* __restrict__ out, float* __restrict__ outp,
        int* __restrict__ pooledi, int* __restrict__ done) {
    __shared__ __align__(16) int2 shE[16][32];        // 4 KB
    __shared__ __align__(16) f16 X[16 * X2STRIDE];    // 4.25 KB
    __shared__ float pool_mx[C2];
    __shared__ float pool_part[4][C2];
    __shared__ int win_s[2];
    int tid   = threadIdx.x;
    int wslot = tid >> 6;
    int lane  = tid & 63;
    int r     = tid >> 5;          // 0..15: node slot
    int l     = tid & 31;
    int row0  = blockIdx.x * 16;   // 1250 blocks
    int2* E = shE[r];
    const char* xb = (const char*)xw2h + 8 * l;       // lane's f16x4 column base

    // ---- phase 1: one node per half-wave, fixed-8-group gather ----
    {
        int n = row0 + r;
        int beg = n * CAP, deg = deg_arr[n];
        float sd = s_dst2[n];
        float ldn = 0.f, a0 = 0.f, a1 = 0.f, a2 = 0.f, a3 = 0.f;

        for (int c0 = 0; c0 < deg; c0 += 32) {
            int dc = min(deg - c0, 32);
            bool act = l < dc;
            int s_e = csr_src[beg + c0 + min(l, dc - 1)];
            float e = s_src2[s_e] + sd;
            e = (e >= 0.f) ? e : 0.2f * e;
            float p = act ? __expf(e) : 0.f;       // pad lanes: exact 0
            float su = p;
#pragma unroll
            for (int off = 16; off >= 1; off >>= 1) su += __shfl_xor(su, off);
            ldn += su;

            E[l] = make_int2(s_e << 8, __float_as_int(p));  // BYTE offset: 256 B row
            asm volatile("s_waitcnt lgkmcnt(0)" ::: "memory");

            // FIXED 8 groups: compile-time trip -> full unroll, loads hoisted
#pragma unroll
            for (int i = 0; i < 32; i += 4) {
                int4 e01 = *(const int4*)&E[i];       // {off0,p0,off1,p1}
                int4 e23 = *(const int4*)&E[i + 2];
                f16x4 v0 = *(const f16x4*)(xb + e01.x);
                f16x4 v1 = *(const f16x4*)(xb + e01.z);
                f16x4 v2 = *(const f16x4*)(xb + e23.x);
                f16x4 v3 = *(const f16x4*)(xb + e23.z);
                float p0 = __int_as_float(e01.y), p1 = __int_as_float(e01.w);
                float p2 = __int_as_float(e23.y), p3 = __int_as_float(e23.w);
                a0 += p0 * (float)v0[0] + p1 * (float)v1[0] + p2 * (float)v2[0] + p3 * (float)v3[0];
                a1 += p0 * (float)v0[1] + p1 * (float)v1[1] + p2 * (float)v2[1] + p3 * (float)v3[1];
                a2 += p0 * (float)v0[2] + p1 * (float)v1[2] + p2 * (float)v2[2] + p3 * (float)v3[2];
                a3 += p0 * (float)v0[3] + p1 * (float)v1[3] + p2 * (float)v2[3] + p3 * (float)v3[3];
            }
            asm volatile("s_waitcnt lgkmcnt(0)" ::: "memory");   // E reads done before rewrite
        }

        float linv = 1.f / fmaxf(ldn, 1e-16f);
        float4 bb = *(const float4*)(b2 + 4 * l);
        f16x4 o;
        o[0] = (f16)fmaxf(a0 * linv + bb.x, 0.f);
        o[1] = (f16)fmaxf(a1 * linv + bb.y, 0.f);
        o[2] = (f16)fmaxf(a2 * linv + bb.z, 0.f);
        o[3] = (f16)fmaxf(a3 * linv + bb.w, 0.f);
        *(f16x4*)&X[r * X2STRIDE + 4 * l] = o;
    }
    __syncthreads();

    // ---- phase 2a: fc MFMA — wave w covers col-tile w ----
    int quad = lane >> 4, col = lane & 15;
    floatx4 acc = {0.f, 0.f, 0.f, 0.f};
    const f16x8* pb = (const f16x8*)FCp;
#pragma unroll
    for (int kb = 0; kb < 4; kb++) {
        f16x8 a = *(const f16x8*)&X[col * X2STRIDE + kb * 32 + quad * 8];
        f16x8 b = pb[(kb * 8 + wslot) * 64 + lane];
        acc = __builtin_amdgcn_mfma_f32_16x16x32_f16(a, b, acc, 0, 0, 0);
    }
    float bias = fcb[wslot * 16 + col];
#pragma unroll
    for (int reg = 0; reg < 4; reg++) {
        int row = row0 + quad * 4 + reg;
        out[(size_t)row * C2 + wslot * 16 + col] = fmaxf(acc[reg] + bias, 0.f);
    }

    // ---- phase 2b: tile-local pooling max + atomicMax (threads 0..127) ----
    int gA = row0 / PER;
    int gB = (row0 + 15) / PER;
    if (tid < C2) {
        int c = tid;
        float mA = 0.f, mB = 0.f;        // x2 >= 0, 0 is identity
#pragma unroll
        for (int rr = 0; rr < 16; rr++) {
            float v = (float)X[rr * X2STRIDE + c];
            if ((row0 + rr) / PER == gA) mA = fmaxf(mA, v);
            else                         mB = fmaxf(mB, v);
        }
        atomicMax(&pooledi[gA * C2 + c], __float_as_int(mA));
        if (gB != gA) atomicMax(&pooledi[gB * C2 + c], __float_as_int(mB));
    }
    __syncthreads();   // barrier drains the atomics for the whole block

    // ---- phase 2c: distributed pooled fc (winner = 13th tile of a graph) ----
    if (tid == 0) {
        __threadfence();                               // publish our maxes
        int tA = atomicAdd(&done[gA], 1);
        int wA = (tA == 12);
        int wB = 0;
        if (gB != gA) { int tB = atomicAdd(&done[gB], 1); wB = (tB == 12); }
        win_s[0] = wA; win_s[1] = wB;
    }
    __syncthreads();

    auto pool_fc = [&](int g2) {
        int t = tid;
        if (t < C2)   // coherent read of the finished maxes (atomic returns old)
            pool_mx[t] = __int_as_float(atomicMax(&pooledi[g2 * C2 + t], 0));
        __syncthreads();
        int pc = t & (C2 - 1), piece = t >> 7;          // 4 pieces x 32 k-rows
        float acc2 = 0.f;
        const float* fw = fcw + (size_t)(piece * 32) * C2 + pc;
        const float* mp = pool_mx + piece * 32;
        for (int k = 0; k < 32; k++) acc2 += mp[k] * fw[(size_t)k * C2];
        pool_part[piece][pc] = acc2;
        __syncthreads();
        if (piece == 0)
            outp[(size_t)g2 * C2 + pc] = fmaxf(pool_part[0][pc] + pool_part[1][pc] +
                                               pool_part[2][pc] + pool_part[3][pc] + fcb[pc], 0.f);
    };
    if (win_s[0]) pool_fc(gA);
    if (win_s[1]) pool_fc(gB);
}

// ---------------------------------------------------------------------------
extern "C" void kernel_launch(void* const* d_in, const int* in_sizes, int n_in,
                              void* d_out, int out_size, void* d_ws, size_t ws_size,
                              hipStream_t stream) {
    const float* feats = (const float*)d_in[0];
    const int*   ei    = (const int*)d_in[1];
    const float* W1  = (const float*)d_in[4];
    const float* a1s = (const float*)d_in[5];
    const float* a1d = (const float*)d_in[6];
    const float* b1  = (const float*)d_in[7];
    const float* W2  = (const float*)d_in[8];
    const float* a2s = (const float*)d_in[9];
    const float* a2d = (const float*)d_in[10];
    const float* b2  = (const float*)d_in[11];
    const float* fcw = (const float*)d_in[12];
    const float* fcb = (const float*)d_in[13];

    float* out_main = (float*)d_out;                        // [20000,128]
    float* out_pool = (float*)d_out + (size_t)N_NODES * C2; // [100,128]

    char* p = (char*)d_ws;
    auto alloc = [&](size_t bytes) {
        char* r = p;
        p += (bytes + 255) & ~(size_t)255;
        return r;
    };
    unsigned short* W2p  = (unsigned short*)alloc(sizeof(short) * C1 * C2);
    unsigned short* W1p  = (unsigned short*)alloc(sizeof(short) * HEADS * F_IN * F_IN);
    f16*   FCp     = (f16*)alloc(sizeof(f16) * C2 * C2);
    f16*   feats16 = (f16*)alloc(sizeof(f16) * (size_t)N_NODES * F_IN);
    f16*   xw2h    = (f16*)alloc(sizeof(f16) * (size_t)N_NODES * C2);
    float* s1s    = (float*)alloc(sizeof(float) * N_NODES * SSTRIDE);
    float* s1d    = (float*)alloc(sizeof(float) * N_NODES * SSTRIDE);
    float* s2s    = (float*)alloc(sizeof(float) * N_NODES);
    float* s2d    = (float*)alloc(sizeof(float) * N_NODES);
    float* wsF    = (float*)alloc(sizeof(float) * C1);
    float* wdF    = (float*)alloc(sizeof(float) * C1);
    // zero region: cursor + pooledi + done, zeroed by fold_zero_kernel
    int* zeros   = (int*)alloc(sizeof(int) * ((NZCNT + 63) & ~63));
    int* cursor  = zeros;
    int* pooledi = zeros + N_NODES;
    int* done    = zeros + N_NODES + NB * C2;
    int* csr_src = (int*)alloc(sizeof(int) * N_NODES * CAP); // bucket CSR

    fold_zero_kernel<<<1 + (((NZCNT + 3) / 4 + 255) / 256), 256, 0, stream>>>(
        W1, a1s, a1d, wsF, wdF, zeros);

    mega_prep_kernel<<<SCAT_BLOCKS + SCORE_BLOCKS + W2P_BLOCKS + W1P_BLOCKS + FCP_BLOCKS + F16_BLOCKS,
                       256, 0, stream>>>(
        ei, cursor, csr_src, feats, feats16, W1, W1p, W2, W2p, fcw, FCp,
        wsF, wdF, s1s, s1d);

    agg1h1g2_kernel<<<1250, 512, 0, stream>>>(feats16, s1s, s1d, cursor, csr_src,
                                              W1p, b1, W2p, a2s, a2d, xw2h, s2s, s2d);
    agg2fc_kernel<<<1250, 512, 0, stream>>>(xw2h, s2s, s2d, cursor, csr_src, b2,
                                            FCp, fcb, fcw, out_main, out_pool,
                                            pooledi, done);
}

// Round 9
// 155.930 us; speedup vs baseline: 1.2354x; 1.2354x over previous
//
#include <hip/hip_runtime.h>

// Problem constants (fixed by the reference)
#define N_NODES 20000
#define N_EDGES 320000
#define ETOT    (N_EDGES + N_NODES)   // edges + self-loops = 340000
#define HEADS   10
#define F_IN    32
#define C1      (HEADS * F_IN)        // 320
#define C2      128
#define NB      100
#define PER     200
#define CAP     96                    // CSR bucket capacity (max in-degree << 96)
#define SSTRIDE 12                    // padded score row stride (floats, 48B = 16B-aligned)
#define HSTRIDE 328                   // padded tile row stride (ushort); 328*2=656 is 16B-aligned
#define X2STRIDE 136                  // padded x2-tile row stride (f16); 136*2=272 is 16B-aligned
#define NZCNT   (N_NODES + NB * C2)   // cursor + pooledi (ints)

typedef __attribute__((ext_vector_type(8))) short bf16x8;   // MFMA A/B frag (4 VGPRs)
typedef __attribute__((ext_vector_type(4))) float floatx4;  // MFMA C/D frag
typedef _Float16 f16;
typedef _Float16 f16x2 __attribute__((ext_vector_type(2)));
typedef _Float16 f16x4 __attribute__((ext_vector_type(4)));
typedef _Float16 f16x8 __attribute__((ext_vector_type(8)));

static __device__ __forceinline__ unsigned short f2bf(float f) {
    unsigned int u = __float_as_uint(f);
    unsigned int r = (u + 0x7fffu + ((u >> 16) & 1u)) >> 16;   // RNE
    return (unsigned short)r;
}

// ---------------------------------------------------------------------------
// Fold + zero kernel: block 0 computes the W1-fold ONCE (was redundantly
// recomputed by all 313 SCORE blocks); blocks 1..N zero cursor/pooledi
// (replaces the hipMemsetAsync dispatch).
// ---------------------------------------------------------------------------
__global__ __launch_bounds__(256) void fold_zero_kernel(
        const float* __restrict__ W1, const float* __restrict__ a1s,
        const float* __restrict__ a1d, float* __restrict__ wsF,
        float* __restrict__ wdF, int* __restrict__ zeros) {
    unsigned int b = blockIdx.x;
    int t = threadIdx.x;
    if (b == 0) {
        for (int o = t; o < C1; o += 256) {
            int k = o & 31, h = o >> 5;
            float ss = 0.f, dd = 0.f;
#pragma unroll
            for (int f = 0; f < F_IN; f++) {
                float wv = W1[k * C1 + h * 32 + f];
                ss += wv * a1s[h * 32 + f];
                dd += wv * a1d[h * 32 + f];
            }
            wsF[k * HEADS + h] = ss;
            wdF[k * HEADS + h] = dd;
        }
        return;
    }
    // zero region, int4 stores (region is 256B-aligned, alloc padded)
    int i = (b - 1) * 256 + t;                 // int4 index
    const int n4 = (NZCNT + 3) / 4;
    if (i < n4) {
        int4 z = {0, 0, 0, 0};
        ((int4*)zeros)[i] = z;
    }
}

// ---------------------------------------------------------------------------
// Mega prep: CSR scatter + layer-1 scores (folded WA) + feats->f16 (emitted
// by the SCORE branch from its in-register feats stream — round 9: removes
// the separate 625-block F16 branch and a redundant 2.56MB read) + W2/W1/FC
// B-frag prep.
// ---------------------------------------------------------------------------
#define SCAT_BLOCKS  ((ETOT + 255) / 256)               // 1329
#define SCORE_BLOCKS ((N_NODES + 63) / 64)              // 313
#define W2P_BLOCKS   ((C1 * C2 + 255) / 256)            // 160
#define W1P_BLOCKS   ((HEADS * F_IN * F_IN + 255) / 256)// 40
#define FCP_BLOCKS   ((C2 * C2 + 255) / 256)            // 64
__global__ __launch_bounds__(256) void mega_prep_kernel(
        const int* __restrict__ ei, int* __restrict__ cursor, int* __restrict__ csr_src,
        const float* __restrict__ feats, f16* __restrict__ feats16,
        const float* __restrict__ W1, unsigned short* __restrict__ W1p,
        const float* __restrict__ W2, unsigned short* __restrict__ W2p,
        const float* __restrict__ fcw, f16* __restrict__ FCp,
        const float* __restrict__ wsF, const float* __restrict__ wdF,
        float* __restrict__ s_src, float* __restrict__ s_dst) {
    unsigned int b = blockIdx.x;
    if (b < SCAT_BLOCKS) {
        int e = b * 256 + threadIdx.x;
        if (e >= ETOT) return;
        int s, d;
        if (e < N_EDGES) { s = ei[e]; d = ei[N_EDGES + e]; }
        else             { s = e - N_EDGES; d = s; }
        int pos = atomicAdd(&cursor[d], 1);
        csr_src[(size_t)d * CAP + pos] = s;
        return;
    }
    b -= SCAT_BLOCKS;
    if (b < SCORE_BLOCKS) {
        __shared__ __align__(16) float A[64 * F_IN];   // 8 KB
        __shared__ float Ws[C1], Wd[C1];
        int t = threadIdx.x;
        // load the pre-folded attention-through-W1 vectors (2.5 KB total)
        for (int o = t; o < C1; o += 256) {
            Ws[o] = wsF[o];
            Wd[o] = wdF[o];
        }
        int n0 = b * 64;
        int nrows = min(64, N_NODES - n0);
        const float4* fs = (const float4*)(feats + (size_t)n0 * F_IN);
        float4* Af = (float4*)A;
        // stage feats into LDS AND emit feats16 from the register value
        for (int i = t; i < nrows * 8; i += 256) {
            float4 v = fs[i];
            Af[i] = v;
            f16x4 h4 = {(f16)v.x, (f16)v.y, (f16)v.z, (f16)v.w};
            *(f16x4*)(feats16 + (size_t)n0 * F_IN + 4 * i) = h4;
        }
        __syncthreads();
        for (int o = t; o < nrows * HEADS; o += 256) {
            int nl = o / HEADS, h = o - nl * HEADS;
            const float* ar = A + nl * F_IN;
            float ss = 0.f, dd = 0.f;
#pragma unroll
            for (int k = 0; k < F_IN; k++) {
                float av = ar[k];
                ss += av * Ws[k * HEADS + h];
                dd += av * Wd[k * HEADS + h];
            }
            s_src[(size_t)(n0 + nl) * SSTRIDE + h] = ss;
            s_dst[(size_t)(n0 + nl) * SSTRIDE + h] = dd;
        }
        return;
    }
    b -= SCORE_BLOCKS;
    if (b < W2P_BLOCKS) {
        int o = b * 256 + threadIdx.x;   // 40960
        if (o >= C1 * C2) return;
        int j    = o & 7;
        int lane = (o >> 3) & 63;
        int ct   = (o >> 9) & 7;
        int kb   = o >> 12;
        int k = kb * 32 + (lane >> 4) * 8 + j;
        int n = ct * 16 + (lane & 15);
        W2p[o] = f2bf(W2[k * C2 + n]);
        return;
    }
    b -= W2P_BLOCKS;
    if (b < W1P_BLOCKS) {
        int o = b * 256 + threadIdx.x;   // 10240
        if (o >= HEADS * F_IN * F_IN) return;
        int j    = o & 7;
        int lane = (o >> 3) & 63;
        int ct   = (o >> 9) & 1;
        int h    = o >> 10;
        int k = (lane >> 4) * 8 + j;
        int f = ct * 16 + (lane & 15);
        W1p[o] = f2bf(W1[k * C1 + h * 32 + f]);
        return;
    }
    b -= W1P_BLOCKS;
    {
        int o = b * 256 + threadIdx.x;   // 16384
        if (o >= C2 * C2) return;
        int j    = o & 7;
        int lane = (o >> 3) & 63;
        int ct   = (o >> 9) & 7;
        int kb   = o >> 12;
        int k = kb * 32 + (lane >> 4) * 8 + j;
        int n = ct * 16 + (lane & 15);
        FCp[o] = (f16)fcw[k * C2 + n];
    }
}

// ---------------------------------------------------------------------------
// FUSED layer-1 aggregation + h1 transform + gemm2.  512 threads, one node
// per 32-lane half-wave, fixed 8-group gather (R7 structure, unchanged).
// ---------------------------------------------------------------------------
__global__ __launch_bounds__(512) void agg1h1g2_kernel(
        const f16* __restrict__ feats16, const float* __restrict__ s_src,
        const float* __restrict__ s_dst, const int* __restrict__ deg_arr,
        const int* __restrict__ csr_src,
        const unsigned short* __restrict__ W1p, const float* __restrict__ b1,
        const unsigned short* __restrict__ W2p,
        const float* __restrict__ a_src, const float* __restrict__ a_dst,
        f16* __restrict__ xw2h, float* __restrict__ s_src2, float* __restrict__ s_dst2) {
    union Smem {
        struct { f16 P[16][HEADS * 32]; int S[16][32]; } p1;  // 10 KB + 2 KB
        unsigned short H[16 * HSTRIDE];                       // 10.25 KB
    };
    __shared__ __align__(16) Smem u;
    __shared__ __align__(16) unsigned short G[16 * HSTRIDE];  // gn tile, bf16
    __shared__ float redS[8][16], redD[8][16];

    int tid   = threadIdx.x;
    int wslot = tid >> 6;          // 0..7
    int lane  = tid & 63;
    int r     = tid >> 5;          // 0..15: node slot (one per half-wave)
    int l     = tid & 31;          // k-index and edge-slot
    int row0  = blockIdx.x * 16;   // 1250 blocks x 16 nodes
    f16* P = u.p1.P[r];
    int* S = u.p1.S[r];
    const f16x2 ones = {(f16)1.f, (f16)1.f};
    const char* fb = (const char*)feats16 + 2 * l;   // lane's k-column base

    // ---- phase 1: one node per half-wave ----
    {
        int n = row0 + r;
        int beg = n * CAP, deg = deg_arr[n];
        const float* sdp = s_dst + (size_t)n * SSTRIDE;
        float sd[10];
        {
            float4 v0 = *(const float4*)(sdp);
            float4 v1 = *(const float4*)(sdp + 4);
            float2 v2 = *(const float2*)(sdp + 8);
            sd[0]=v0.x; sd[1]=v0.y; sd[2]=v0.z; sd[3]=v0.w;
            sd[4]=v1.x; sd[5]=v1.y; sd[6]=v1.z; sd[7]=v1.w;
            sd[8]=v2.x; sd[9]=v2.y;
        }
        float g[10], la[10];
#pragma unroll
        for (int h = 0; h < 10; h++) { g[h] = 0.f; la[h] = 0.f; }

        for (int c0 = 0; c0 < deg; c0 += 32) {   // lockstep max over wave's 2 halves
            int dc = min(deg - c0, 32);
            bool act = l < dc;
            int s_e = csr_src[beg + c0 + min(l, dc - 1)];
            const float* ssp = s_src + (size_t)s_e * SSTRIDE;
            float ss[10];
            {
                float4 v0 = *(const float4*)(ssp);
                float4 v1 = *(const float4*)(ssp + 4);
                float2 v2 = *(const float2*)(ssp + 8);
                ss[0]=v0.x; ss[1]=v0.y; ss[2]=v0.z; ss[3]=v0.w;
                ss[4]=v1.x; ss[5]=v1.y; ss[6]=v1.z; ss[7]=v1.w;
                ss[8]=v2.x; ss[9]=v2.y;
            }
            float p[10];
#pragma unroll
            for (int h = 0; h < 10; h++) {
                float e0 = ss[h] + sd[h];
                e0 = (e0 >= 0.f) ? e0 : 0.2f * e0;   // leaky_relu(0.2)
                p[h] = act ? __expf(e0) : 0.f;       // pad lanes: exact 0
            }
            S[l] = s_e << 6;   // BYTE offset: row = 32 f16 = 64 B
#pragma unroll
            for (int h = 0; h < 10; h++) P[h * 32 + l] = (f16)p[h];
            asm volatile("s_waitcnt lgkmcnt(0)" ::: "memory");   // staging visible

            // FIXED 8 groups: compile-time trip -> full unroll, loads hoisted
#pragma unroll
            for (int i = 0; i < 32; i += 4) {
                int4 ss4 = *(const int4*)&S[i];
                f16x2 v01, v23;
                v01.x = *(const f16*)(fb + ss4.x);
                v01.y = *(const f16*)(fb + ss4.y);
                v23.x = *(const f16*)(fb + ss4.z);
                v23.y = *(const f16*)(fb + ss4.w);
#pragma unroll
                for (int h = 0; h < 10; h++) {
                    f16x4 pp = *(const f16x4*)&P[h * 32 + i];
                    f16x2 p01 = {pp[0], pp[1]};
                    f16x2 p23 = {pp[2], pp[3]};
                    g[h]  = __builtin_amdgcn_fdot2(p01, v01, g[h], false);
                    g[h]  = __builtin_amdgcn_fdot2(p23, v23, g[h], false);
                    la[h] = __builtin_amdgcn_fdot2(p01, ones, la[h], false);
                    la[h] = __builtin_amdgcn_fdot2(p23, ones, la[h], false);
                }
            }
            asm volatile("s_waitcnt lgkmcnt(0)" ::: "memory");   // P/S reads done before rewrite
        }
        unsigned short* gr = &G[r * HSTRIDE + l];
#pragma unroll
        for (int h = 0; h < 10; h++)
            gr[h * 32] = f2bf(g[h] / fmaxf(la[h], 1e-16f));
    }
    __syncthreads();   // G complete; P/S dead -> union region becomes H

    // ---- phase 2a: h1 = elu(G @ W1 + b1), heads strided over 8 waves ----
    int quad = lane >> 4, col = lane & 15;
    for (int h = wslot; h < 10; h += 8) {
        bf16x8 a = *(const bf16x8*)&G[col * HSTRIDE + h * 32 + quad * 8];
        bf16x8 bA = ((const bf16x8*)W1p)[(h * 2 + 0) * 64 + lane];
        bf16x8 bB = ((const bf16x8*)W1p)[(h * 2 + 1) * 64 + lane];
        floatx4 z = {0.f, 0.f, 0.f, 0.f};
        floatx4 c0 = __builtin_amdgcn_mfma_f32_16x16x32_bf16(a, bA, z, 0, 0, 0);
        floatx4 c1 = __builtin_amdgcn_mfma_f32_16x16x32_bf16(a, bB, z, 0, 0, 0);
        float bias0 = b1[h * 32 + col];
        float bias1 = b1[h * 32 + 16 + col];
#pragma unroll
        for (int reg = 0; reg < 4; reg++) {
            int rr = quad * 4 + reg;
            float o0 = c0[reg] + bias0;
            float o1 = c1[reg] + bias1;
            o0 = (o0 > 0.f) ? o0 : (__expf(o0) - 1.f);
            o1 = (o1 > 0.f) ? o1 : (__expf(o1) - 1.f);
            u.H[rr * HSTRIDE + h * 32 + col]      = f2bf(o0);
            u.H[rr * HSTRIDE + h * 32 + 16 + col] = f2bf(o1);
        }
    }
    __syncthreads();

    // ---- phase 2b: gemm2 — wave w covers col-tile w ----
    floatx4 acc = {0.f, 0.f, 0.f, 0.f};
    const bf16x8* pb = (const bf16x8*)W2p;
#pragma unroll
    for (int kb = 0; kb < 10; kb++) {
        bf16x8 a = *(const bf16x8*)&u.H[col * HSTRIDE + kb * 32 + quad * 8];
        bf16x8 b = pb[(kb * 8 + wslot) * 64 + lane];
        acc = __builtin_amdgcn_mfma_f32_16x16x32_bf16(a, b, acc, 0, 0, 0);
    }
    float asv = a_src[wslot * 16 + col];
    float adv = a_dst[wslot * 16 + col];
#pragma unroll
    for (int reg = 0; reg < 4; reg++) {
        int row = row0 + quad * 4 + reg;
        float v = acc[reg];
        xw2h[(size_t)row * C2 + wslot * 16 + col] = (f16)v;
        float vs = v * asv, vd = v * adv;
#pragma unroll
        for (int off = 8; off >= 1; off >>= 1) {
            vs += __shfl_xor(vs, off);
            vd += __shfl_xor(vd, off);
        }
        if (col == 0) { redS[wslot][quad * 4 + reg] = vs; redD[wslot][quad * 4 + reg] = vd; }
    }
    __syncthreads();
    if (wslot == 0) {
        if (lane < 16) {
            float s = 0.f;
#pragma unroll
            for (int w2 = 0; w2 < 8; w2++) s += redS[w2][lane];
            s_src2[row0 + lane] = s;
        } else if (lane < 32) {
            int r2 = lane - 16;
            float d = 0.f;
#pragma unroll
            for (int w2 = 0; w2 < 8; w2++) d += redD[w2][r2];
            s_dst2[row0 + r2] = d;
        }
    }
}

// ---------------------------------------------------------------------------
// Fused layer-2 aggregation + fc.  512 threads, one node per half-wave,
// fixed 8-group gather.  Pooling via tile-local max + atomicMax; pooled fc
// is a SEPARATE kernel — the distributed-completion fusion costs ~30us of
// device-scope atomic drains per block (measured 3x: R2 71.6, R5 61.8,
// R8 59.9 vs <44 without it, across different gather structures). Never fuse.
// ---------------------------------------------------------------------------
__global__ __launch_bounds__(512) void agg2fc_kernel(
        const f16* __restrict__ xw2h, const float* __restrict__ s_src2,
        const float* __restrict__ s_dst2, const int* __restrict__ deg_arr,
        const int* __restrict__ csr_src, const float* __restrict__ b2,
        const f16* __restrict__ FCp, const float* __restrict__ fcb,
        float* __restrict__ out, int* __restrict__ pooledi) {
    __shared__ __align__(16) int2 shE[16][32];        // 4 KB
    __shared__ __align__(16) f16 X[16 * X2STRIDE];    // 4.25 KB
    int tid   = threadIdx.x;
    int wslot = tid >> 6;
    int lane  = tid & 63;
    int r     = tid >> 5;          // 0..15: node slot
    int l     = tid & 31;
    int row0  = blockIdx.x * 16;   // 1250 blocks
    int2* E = shE[r];
    const char* xb = (const char*)xw2h + 8 * l;       // lane's f16x4 column base

    // ---- phase 1: one node per half-wave, fixed-8-group gather ----
    {
        int n = row0 + r;
        int beg = n * CAP, deg = deg_arr[n];
        float sd = s_dst2[n];
        float ldn = 0.f, a0 = 0.f, a1 = 0.f, a2 = 0.f, a3 = 0.f;

        for (int c0 = 0; c0 < deg; c0 += 32) {
            int dc = min(deg - c0, 32);
            bool act = l < dc;
            int s_e = csr_src[beg + c0 + min(l, dc - 1)];
            float e = s_src2[s_e] + sd;
            e = (e >= 0.f) ? e : 0.2f * e;
            float p = act ? __expf(e) : 0.f;       // pad lanes: exact 0
            float su = p;
#pragma unroll
            for (int off = 16; off >= 1; off >>= 1) su += __shfl_xor(su, off);
            ldn += su;

            E[l] = make_int2(s_e << 8, __float_as_int(p));  // BYTE offset: 256 B row
            asm volatile("s_waitcnt lgkmcnt(0)" ::: "memory");

            // FIXED 8 groups: compile-time trip -> full unroll, loads hoisted
#pragma unroll
            for (int i = 0; i < 32; i += 4) {
                int4 e01 = *(const int4*)&E[i];       // {off0,p0,off1,p1}
                int4 e23 = *(const int4*)&E[i + 2];
                f16x4 v0 = *(const f16x4*)(xb + e01.x);
                f16x4 v1 = *(const f16x4*)(xb + e01.z);
                f16x4 v2 = *(const f16x4*)(xb + e23.x);
                f16x4 v3 = *(const f16x4*)(xb + e23.z);
                float p0 = __int_as_float(e01.y), p1 = __int_as_float(e01.w);
                float p2 = __int_as_float(e23.y), p3 = __int_as_float(e23.w);
                a0 += p0 * (float)v0[0] + p1 * (float)v1[0] + p2 * (float)v2[0] + p3 * (float)v3[0];
                a1 += p0 * (float)v0[1] + p1 * (float)v1[1] + p2 * (float)v2[1] + p3 * (float)v3[1];
                a2 += p0 * (float)v0[2] + p1 * (float)v1[2] + p2 * (float)v2[2] + p3 * (float)v3[2];
                a3 += p0 * (float)v0[3] + p1 * (float)v1[3] + p2 * (float)v2[3] + p3 * (float)v3[3];
            }
            asm volatile("s_waitcnt lgkmcnt(0)" ::: "memory");   // E reads done before rewrite
        }

        float linv = 1.f / fmaxf(ldn, 1e-16f);
        float4 bb = *(const float4*)(b2 + 4 * l);
        f16x4 o;
        o[0] = (f16)fmaxf(a0 * linv + bb.x, 0.f);
        o[1] = (f16)fmaxf(a1 * linv + bb.y, 0.f);
        o[2] = (f16)fmaxf(a2 * linv + bb.z, 0.f);
        o[3] = (f16)fmaxf(a3 * linv + bb.w, 0.f);
        *(f16x4*)&X[r * X2STRIDE + 4 * l] = o;
    }
    __syncthreads();

    // ---- phase 2a: fc MFMA — wave w covers col-tile w ----
    int quad = lane >> 4, col = lane & 15;
    floatx4 acc = {0.f, 0.f, 0.f, 0.f};
    const f16x8* pb = (const f16x8*)FCp;
#pragma unroll
    for (int kb = 0; kb < 4; kb++) {
        f16x8 a = *(const f16x8*)&X[col * X2STRIDE + kb * 32 + quad * 8];
        f16x8 b = pb[(kb * 8 + wslot) * 64 + lane];
        acc = __builtin_amdgcn_mfma_f32_16x16x32_f16(a, b, acc, 0, 0, 0);
    }
    float bias = fcb[wslot * 16 + col];
#pragma unroll
    for (int reg = 0; reg < 4; reg++) {
        int row = row0 + quad * 4 + reg;
        out[(size_t)row * C2 + wslot * 16 + col] = fmaxf(acc[reg] + bias, 0.f);
    }

    // ---- phase 2b: tile-local pooling max + atomicMax (threads 0..127) ----
    if (tid < C2) {
        int c = tid;
        int gA = row0 / PER;
        int gB = (row0 + 15) / PER;
        float mA = 0.f, mB = 0.f;        // x2 >= 0, 0 is identity
#pragma unroll
        for (int rr = 0; rr < 16; rr++) {
            float v = (float)X[rr * X2STRIDE + c];
            if ((row0 + rr) / PER == gA) mA = fmaxf(mA, v);
            else                         mB = fmaxf(mB, v);
        }
        atomicMax(&pooledi[gA * C2 + c], __float_as_int(mA));
        if (gB != gA) atomicMax(&pooledi[gB * C2 + c], __float_as_int(mB));
    }
}

// ---------------------------------------------------------------------------
// Final pooled fc: relu(pooled @ fc_w + fc_b)  — 100 parallel blocks
// ---------------------------------------------------------------------------
__global__ void poolfc_kernel(const int* __restrict__ pooledi, const float* __restrict__ fcw,
                              const float* __restrict__ fcb, float* __restrict__ outp) {
    __shared__ float mx[C2];
    int g = blockIdx.x, t = threadIdx.x;   // 128
    mx[t] = __int_as_float(pooledi[g * C2 + t]);
    __syncthreads();
    float acc = 0.f;
    for (int k = 0; k < C2; k++) acc += mx[k] * fcw[k * C2 + t];
    outp[g * C2 + t] = fmaxf(acc + fcb[t], 0.f);
}

// ---------------------------------------------------------------------------
extern "C" void kernel_launch(void* const* d_in, const int* in_sizes, int n_in,
                              void* d_out, int out_size, void* d_ws, size_t ws_size,
                              hipStream_t stream) {
    const float* feats = (const float*)d_in[0];
    const int*   ei    = (const int*)d_in[1];
    const float* W1  = (const float*)d_in[4];
    const float* a1s = (const float*)d_in[5];
    const float* a1d = (const float*)d_in[6];
    const float* b1  = (const float*)d_in[7];
    const float* W2  = (const float*)d_in[8];
    const float* a2s = (const float*)d_in[9];
    const float* a2d = (const float*)d_in[10];
    const float* b2  = (const float*)d_in[11];
    const float* fcw = (const float*)d_in[12];
    const float* fcb = (const float*)d_in[13];

    float* out_main = (float*)d_out;                        // [20000,128]
    float* out_pool = (float*)d_out + (size_t)N_NODES * C2; // [100,128]

    char* p = (char*)d_ws;
    auto alloc = [&](size_t bytes) {
        char* r = p;
        p += (bytes + 255) & ~(size_t)255;
        return r;
    };
    unsigned short* W2p  = (unsigned short*)alloc(sizeof(short) * C1 * C2);
    unsigned short* W1p  = (unsigned short*)alloc(sizeof(short) * HEADS * F_IN * F_IN);
    f16*   FCp     = (f16*)alloc(sizeof(f16) * C2 * C2);
    f16*   feats16 = (f16*)alloc(sizeof(f16) * (size_t)N_NODES * F_IN);
    f16*   xw2h    = (f16*)alloc(sizeof(f16) * (size_t)N_NODES * C2);
    float* s1s    = (float*)alloc(sizeof(float) * N_NODES * SSTRIDE);
    float* s1d    = (float*)alloc(sizeof(float) * N_NODES * SSTRIDE);
    float* s2s    = (float*)alloc(sizeof(float) * N_NODES);
    float* s2d    = (float*)alloc(sizeof(float) * N_NODES);
    float* wsF    = (float*)alloc(sizeof(float) * C1);
    float* wdF    = (float*)alloc(sizeof(float) * C1);
    // zero region: cursor + pooledi, zeroed by fold_zero_kernel (int4 stores)
    int* zeros   = (int*)alloc(sizeof(int) * ((NZCNT + 63) & ~63));
    int* cursor  = zeros;
    int* pooledi = zeros + N_NODES;
    int* csr_src = (int*)alloc(sizeof(int) * N_NODES * CAP); // bucket CSR

    fold_zero_kernel<<<1 + (((NZCNT + 3) / 4 + 255) / 256), 256, 0, stream>>>(
        W1, a1s, a1d, wsF, wdF, zeros);

    mega_prep_kernel<<<SCAT_BLOCKS + SCORE_BLOCKS + W2P_BLOCKS + W1P_BLOCKS + FCP_BLOCKS,
                       256, 0, stream>>>(
        ei, cursor, csr_src, feats, feats16, W1, W1p, W2, W2p, fcw, FCp,
        wsF, wdF, s1s, s1d);

    agg1h1g2_kernel<<<1250, 512, 0, stream>>>(feats16, s1s, s1d, cursor, csr_src,
                                              W1p, b1, W2p, a2s, a2d, xw2h, s2s, s2d);
    agg2fc_kernel<<<1250, 512, 0, stream>>>(xw2h, s2s, s2d, cursor, csr_src, b2,
                                            FCp, fcb, out_main, pooledi);
    poolfc_kernel<<<NB, C2, 0, stream>>>(pooledi, fcw, fcb, out_pool);
}